// Round 6
// baseline (171.675 us; speedup 1.0000x reference)
//
#include <hip/hip_runtime.h>

// SDF volume rendering (NeuS/VolSDF-style), float32 in/out.
//
// Per ray (96 samples):
//   alpha_i = 1 - exp(-beta * sigmoid(-sdf_i * beta))
//   t_i     = 1 - alpha_i + 1e-10
//   trans_i = exclusive cumprod of t ;  w_i = alpha_i * trans_i
//   depth   = sum w_i * z_i ;  rgb_c = sum w_i * rgb_{i,c}
//
// R10: R9 (role-split, store-free compute) = 50us, 2.8 TB/s (44% of achiev).
// Wave-lifetime math: compute waves live ~30k cy doing ~2k cy of work --
// they issue 5 loads ONCE, wait cold, run the dependent exp/shfl chain, die.
// vmcnt retires IN ORDER, so R6's pipeline failed because its mid-kernel
// passthrough stores made every later load-wait drain the store path.
// Pipeline WITHOUT stores has never been tried -> R10:
//  * copy role: fully unrolled (exactly 3 f4/thread/array), 6 loads in
//    flight then 6 nontemporal stores. Parity-interleaved with compute
//    blocks to mix the read-heavy and write-heavy streams.
//  * compute role: 4 rays per 32-lane group, A/B register double-buffer,
//    no guards on the fast path; output stores issued AFTER the next load
//    pack so no load ever waits behind a store (in-order vmcnt).
//  * __launch_bounds__(256,6): VGPR cap ~85 so the 2-set pipeline (~55
//    regs) cannot spill; 24 waves/CU is ample with per-wave ILP.

#define SDFR_NS 96
#define SDFR_HALF 2048   // 2048 copy blocks + 2048 compute blocks (parity)

struct f3 { float x, y, z; };                              // 12B -> dwordx3
typedef float fv4 __attribute__((ext_vector_type(4)));     // true vector type

__device__ __forceinline__ void compute_ray(
    int l, float beta,
    const f3& sv, const f3& zv, const f3& ca, const f3& cb, const f3& cc,
    float& depth, float& r0, float& r1, float& r2)
{
    // sigmoid(-s*beta) = 1/(1+exp(s*beta)); e = exp(-beta*sig)
    const float e0 = __expf(-beta * __builtin_amdgcn_rcpf(1.0f + __expf(sv.x * beta)));
    const float e1 = __expf(-beta * __builtin_amdgcn_rcpf(1.0f + __expf(sv.y * beta)));
    const float e2 = __expf(-beta * __builtin_amdgcn_rcpf(1.0f + __expf(sv.z * beta)));
    const float a0 = 1.0f - e0, t0 = e0 + 1e-10f;
    const float a1 = 1.0f - e1, t1 = e1 + 1e-10f;
    const float a2 = 1.0f - e2, t2 = e2 + 1e-10f;

    // 32-lane exclusive prefix product of per-lane local product
    float scan = t0 * t1 * t2;
    #pragma unroll
    for (int d = 1; d < 32; d <<= 1) {
        float v = __shfl_up(scan, d, 32);
        if (l >= d) scan *= v;
    }
    float E = __shfl_up(scan, 1, 32);
    if (l == 0) E = 1.0f;

    const float w0 = a0 * E;
    const float w1 = a1 * E * t0;
    const float w2 = a2 * E * t0 * t1;

    depth = w0 * zv.x + w1 * zv.y + w2 * zv.z;
    r0    = w0 * ca.x + w1 * cb.x + w2 * cc.x;
    r1    = w0 * ca.y + w1 * cb.y + w2 * cc.y;
    r2    = w0 * ca.z + w1 * cb.z + w2 * cc.z;

    #pragma unroll
    for (int d = 16; d >= 1; d >>= 1) {
        depth += __shfl_xor(depth, d, 32);
        r0    += __shfl_xor(r0, d, 32);
        r1    += __shfl_xor(r1, d, 32);
        r2    += __shfl_xor(r2, d, 32);
    }
}

__global__ __launch_bounds__(256, 6) void sdf_render_kernel(
    const float* __restrict__ rgb,      // [N*96*3]
    const float* __restrict__ sdf,      // [N*96]
    const float* __restrict__ z_vals,   // [N*96]
    const int*   __restrict__ beta_p,   // scalar (int32, or f32 bit pattern)
    float* __restrict__ out_depth,      // [N]
    float* __restrict__ out_rgb,        // [N,3]
    float* __restrict__ out_sdf,        // [N*96]
    float* __restrict__ out_z,          // [N*96]
    int n_rays)
{
    const int t    = threadIdx.x;
    const int half = blockIdx.x >> 1;

    if ((blockIdx.x & 1) == 0) {
        // ---------------- copy role: pure float4 stream ----------------
        const int n4     = (n_rays * SDFR_NS) / 4;   // 1,572,864 @ N=65536
        const int stride = SDFR_HALF * 256;          // 524,288
        const int i0 = half * 256 + t;
        const int i1 = i0 + stride;
        const int i2 = i0 + 2 * stride;
        const fv4* __restrict__ s4 = (const fv4*)sdf;
        const fv4* __restrict__ z4 = (const fv4*)z_vals;
        fv4* __restrict__ os4 = (fv4*)out_sdf;
        fv4* __restrict__ oz4 = (fv4*)out_z;

        if (i2 < n4) {   // N=65536: exact, always taken
            const fv4 a0 = s4[i0], a1 = s4[i1], a2 = s4[i2];
            const fv4 b0 = z4[i0], b1 = z4[i1], b2 = z4[i2];
            __builtin_amdgcn_sched_barrier(0);  // all 6 loads in flight
            __builtin_nontemporal_store(a0, os4 + i0);
            __builtin_nontemporal_store(a1, os4 + i1);
            __builtin_nontemporal_store(a2, os4 + i2);
            __builtin_nontemporal_store(b0, oz4 + i0);
            __builtin_nontemporal_store(b1, oz4 + i1);
            __builtin_nontemporal_store(b2, oz4 + i2);
        } else {
            for (int i = i0; i < n4; i += stride) {
                const fv4 a = s4[i];
                const fv4 b = z4[i];
                __builtin_nontemporal_store(a, os4 + i);
                __builtin_nontemporal_store(b, oz4 + i);
            }
        }
        return;
    }

    // ------------- compute role: 32 lanes/ray, 4 rays/group -------------
    const int g    = t >> 5;          // lane-group 0..7
    const int l    = t & 31;          // lane l owns samples [3l, 3l+3)
    const int base = half * 32;       // 32 rays per compute block

    // beta decode: small int is the value; huge magnitude is an f32 pattern
    int bi = *beta_p;
    float beta;
    if (bi > 1000000 || bi < -1000000) {
        union { int i; float f; } u; u.i = bi; beta = u.f;
    } else {
        beta = (float)bi;
    }

    f3 svA, zvA, caA, cbA, ccA;
    f3 svB, zvB, caB, cbB, ccB;

#define SDFR_LOAD(SFX, RAY)                                         \
    do {                                                            \
        const int sb_ = (RAY) * SDFR_NS + 3 * l;                    \
        const int rb_ = (RAY) * (SDFR_NS * 3) + 9 * l;              \
        sv##SFX = *(const f3*)(sdf    + sb_);                       \
        zv##SFX = *(const f3*)(z_vals + sb_);                       \
        ca##SFX = *(const f3*)(rgb + rb_ + 0);                      \
        cb##SFX = *(const f3*)(rgb + rb_ + 3);                      \
        cc##SFX = *(const f3*)(rgb + rb_ + 6);                      \
    } while (0)

#define SDFR_STORE(RAY, D, R0, R1, R2)                              \
    do {                                                            \
        if (l == 0) {                                               \
            out_depth[(RAY)] = (D);                                 \
            f3 o_; o_.x = (R0); o_.y = (R1); o_.z = (R2);           \
            *(f3*)(out_rgb + (RAY) * 3) = o_;                       \
        }                                                           \
    } while (0)

    if (base + 32 <= n_rays) {
        // fast path: no per-ray guards, 2-deep A/B pipeline
        const int r0_ = base +  0 + g;
        const int r1_ = base +  8 + g;
        const int r2_ = base + 16 + g;
        const int r3_ = base + 24 + g;

        SDFR_LOAD(A, r0_);
        SDFR_LOAD(B, r1_);
        __builtin_amdgcn_sched_barrier(0);   // 10 loads in flight

        float d0, x0, y0, w0_;
        compute_ray(l, beta, svA, zvA, caA, cbA, ccA, d0, x0, y0, w0_);
        SDFR_LOAD(A, r2_);                   // prefetch before the store
        SDFR_STORE(r0_, d0, x0, y0, w0_);    // store AFTER loads (vmcnt order)
        __builtin_amdgcn_sched_barrier(0);

        float d1, x1, y1, w1_;
        compute_ray(l, beta, svB, zvB, caB, cbB, ccB, d1, x1, y1, w1_);
        SDFR_LOAD(B, r3_);
        SDFR_STORE(r1_, d1, x1, y1, w1_);
        __builtin_amdgcn_sched_barrier(0);

        float d2, x2, y2, w2_;
        compute_ray(l, beta, svA, zvA, caA, cbA, ccA, d2, x2, y2, w2_);
        SDFR_STORE(r2_, d2, x2, y2, w2_);

        float d3, x3, y3, w3_;
        compute_ray(l, beta, svB, zvB, caB, cbB, ccB, d3, x3, y3, w3_);
        SDFR_STORE(r3_, d3, x3, y3, w3_);
    } else {
        // tail path (never taken at N=65536): guarded, unpipelined
        for (int p = 0; p < 4; ++p) {
            const int ray = base + p * 8 + g;
            if (ray < n_rays) {
                SDFR_LOAD(A, ray);
                float d_, x_, y_, w_;
                compute_ray(l, beta, svA, zvA, caA, cbA, ccA, d_, x_, y_, w_);
                SDFR_STORE(ray, d_, x_, y_, w_);
            }
        }
    }

#undef SDFR_LOAD
#undef SDFR_STORE
}

extern "C" void kernel_launch(void* const* d_in, const int* in_sizes, int n_in,
                              void* d_out, int out_size, void* d_ws, size_t ws_size,
                              hipStream_t stream) {
    (void)n_in; (void)d_ws; (void)ws_size; (void)out_size;

    const float* rgb    = (const float*)d_in[0];
    const float* sdf    = (const float*)d_in[1];
    const float* z      = (const float*)d_in[2];
    const int*   beta_p = (const int*)d_in[3];

    const int n_rays = in_sizes[1] / SDFR_NS;  // 65536

    // output layout (f32): depth[N] | rgb[N*3] | sdf[N*96] | z[N*96]
    float* out_depth = (float*)d_out;
    float* out_rgb   = out_depth + n_rays;
    float* out_sdf   = out_rgb   + (size_t)n_rays * 3;
    float* out_z     = out_sdf   + (size_t)n_rays * SDFR_NS;

    // parity-interleaved: even blocks copy, odd blocks compute (32 rays each)
    const int grid = 2 * SDFR_HALF;   // 4096
    sdf_render_kernel<<<grid, 256, 0, stream>>>(
        rgb, sdf, z, beta_p, out_depth, out_rgb, out_sdf, out_z, n_rays);
}

// Round 7
// 170.209 us; speedup vs baseline: 1.0086x; 1.0086x over previous
//
#include <hip/hip_runtime.h>

// SDF volume rendering (NeuS/VolSDF-style), float32 in/out.
//
// Per ray (96 samples):
//   alpha_i = 1 - exp(-beta * sigmoid(-sdf_i * beta))
//   t_i     = 1 - alpha_i + 1e-10
//   trans_i = exclusive cumprod of t ;  w_i = alpha_i * trans_i
//   depth   = sum w_i * z_i ;  rgb_c = sum w_i * rgb_{i,c}
//
// R11: the 2x2 of {single-pass vs double-traffic} x {loads-after-stores vs
// store-clean}. R2-R6 = single-pass but poisoned (vmcnt retires IN ORDER:
// any load issued after a store waits for store drain; reloading a stored
// register is a WAW stall -- R6 did exactly that). R9/R10 = store-clean but
// pay a 50MB sdf/z double-read + nt-store L3 eviction (50us, 2.8 TB/s).
// Untried: SINGLE-PASS + ALL 20 LOADS BEFORE ANY STORE, registers never
// reloaded.
//   phase 1: each 32-lane group owns 4 rays; issue all 20 dwordx3 loads
//            (240 B/lane in flight = copy-loop-grade MLP), sched_barrier.
//   phase 2: per set k: {passthrough-store sv_k/zv_k -> compute -> output
//            store}. Stores drain overlapped with compute; no later loads.
// Ideal traffic 164 MB (113 R + 51 W) -> 26us floor at 6.3 TB/s.
// __launch_bounds__(256,4): 128-VGPR cap fits the ~80-reg batch, 16 w/CU.

#define SDFR_NS 96
#define SDFR_RPB 32   // rays per block: 8 lane-groups x 4 rays

struct f3 { float x, y, z; };   // 12B -> global_load/store_dwordx3

__device__ __forceinline__ void compute_ray(
    int l, float beta,
    const f3& sv, const f3& zv, const f3& ca, const f3& cb, const f3& cc,
    float& depth, float& r0, float& r1, float& r2)
{
    // sigmoid(-s*beta) = 1/(1+exp(s*beta)); e = exp(-beta*sig)
    const float e0 = __expf(-beta * __builtin_amdgcn_rcpf(1.0f + __expf(sv.x * beta)));
    const float e1 = __expf(-beta * __builtin_amdgcn_rcpf(1.0f + __expf(sv.y * beta)));
    const float e2 = __expf(-beta * __builtin_amdgcn_rcpf(1.0f + __expf(sv.z * beta)));
    const float a0 = 1.0f - e0, t0 = e0 + 1e-10f;
    const float a1 = 1.0f - e1, t1 = e1 + 1e-10f;
    const float a2 = 1.0f - e2, t2 = e2 + 1e-10f;

    // 32-lane exclusive prefix product of per-lane local product
    float scan = t0 * t1 * t2;
    #pragma unroll
    for (int d = 1; d < 32; d <<= 1) {
        float v = __shfl_up(scan, d, 32);
        if (l >= d) scan *= v;
    }
    float E = __shfl_up(scan, 1, 32);
    if (l == 0) E = 1.0f;

    const float w0 = a0 * E;
    const float w1 = a1 * E * t0;
    const float w2 = a2 * E * t0 * t1;

    depth = w0 * zv.x + w1 * zv.y + w2 * zv.z;
    r0    = w0 * ca.x + w1 * cb.x + w2 * cc.x;
    r1    = w0 * ca.y + w1 * cb.y + w2 * cc.y;
    r2    = w0 * ca.z + w1 * cb.z + w2 * cc.z;

    #pragma unroll
    for (int d = 16; d >= 1; d >>= 1) {
        depth += __shfl_xor(depth, d, 32);
        r0    += __shfl_xor(r0, d, 32);
        r1    += __shfl_xor(r1, d, 32);
        r2    += __shfl_xor(r2, d, 32);
    }
}

__global__ __launch_bounds__(256, 4) void sdf_render_kernel(
    const float* __restrict__ rgb,      // [N*96*3]
    const float* __restrict__ sdf,      // [N*96]
    const float* __restrict__ z_vals,   // [N*96]
    const int*   __restrict__ beta_p,   // scalar (int32, or f32 bit pattern)
    float* __restrict__ out_depth,      // [N]
    float* __restrict__ out_rgb,        // [N,3]
    float* __restrict__ out_sdf,        // [N*96]
    float* __restrict__ out_z,          // [N*96]
    int n_rays)
{
    const int t    = threadIdx.x;
    const int g    = t >> 5;          // lane-group 0..7
    const int l    = t & 31;          // lane l owns samples [3l, 3l+3)
    const int base = blockIdx.x * SDFR_RPB;

    // beta decode: small int is the value; huge magnitude is an f32 pattern
    int bi = *beta_p;
    float beta;
    if (bi > 1000000 || bi < -1000000) {
        union { int i; float f; } u; u.i = bi; beta = u.f;
    } else {
        beta = (float)bi;
    }

    f3 sv0, zv0, ca0, cb0, cc0;
    f3 sv1, zv1, ca1, cb1, cc1;
    f3 sv2, zv2, ca2, cb2, cc2;
    f3 sv3, zv3, ca3, cb3, cc3;

#define SDFR_LOAD(K, RAY)                                           \
    do {                                                            \
        const int sb_ = (RAY) * SDFR_NS + 3 * l;                    \
        const int rb_ = (RAY) * (SDFR_NS * 3) + 9 * l;              \
        sv##K = *(const f3*)(sdf    + sb_);                         \
        zv##K = *(const f3*)(z_vals + sb_);                         \
        ca##K = *(const f3*)(rgb + rb_ + 0);                        \
        cb##K = *(const f3*)(rgb + rb_ + 3);                        \
        cc##K = *(const f3*)(rgb + rb_ + 6);                        \
    } while (0)

#define SDFR_PASS(K, RAY)                                           \
    do {                                                            \
        const int sb_ = (RAY) * SDFR_NS + 3 * l;                    \
        *(f3*)(out_sdf + sb_) = sv##K;                              \
        *(f3*)(out_z   + sb_) = zv##K;                              \
    } while (0)

#define SDFR_RUN(K, RAY)                                            \
    do {                                                            \
        float d_, x_, y_, w_;                                       \
        compute_ray(l, beta, sv##K, zv##K, ca##K, cb##K, cc##K,     \
                    d_, x_, y_, w_);                                \
        if (l == 0) {                                               \
            out_depth[(RAY)] = d_;                                  \
            f3 o_; o_.x = x_; o_.y = y_; o_.z = w_;                 \
            *(f3*)(out_rgb + (RAY) * 3) = o_;                       \
        }                                                           \
    } while (0)

    if (base + SDFR_RPB <= n_rays) {
        const int r0_ = base + g;
        const int r1_ = r0_ + 8;
        const int r2_ = r0_ + 16;
        const int r3_ = r0_ + 24;

        // ---- phase 1: ALL 20 loads issued before anything else ----
        SDFR_LOAD(0, r0_);
        SDFR_LOAD(1, r1_);
        SDFR_LOAD(2, r2_);
        SDFR_LOAD(3, r3_);
        __builtin_amdgcn_sched_barrier(0);

        // ---- phase 2: per set: passthrough store, compute, output ----
        // (stores drain overlapped with compute; no loads follow any store)
        SDFR_PASS(0, r0_);
        SDFR_RUN(0, r0_);
        SDFR_PASS(1, r1_);
        SDFR_RUN(1, r1_);
        SDFR_PASS(2, r2_);
        SDFR_RUN(2, r2_);
        SDFR_PASS(3, r3_);
        SDFR_RUN(3, r3_);
    } else {
        // tail path (never taken at N=65536): guarded, unpipelined
        for (int p = 0; p < 4; ++p) {
            const int ray = base + p * 8 + g;
            if (ray < n_rays) {
                SDFR_LOAD(0, ray);
                SDFR_PASS(0, ray);
                SDFR_RUN(0, ray);
            }
        }
    }

#undef SDFR_LOAD
#undef SDFR_PASS
#undef SDFR_RUN
}

extern "C" void kernel_launch(void* const* d_in, const int* in_sizes, int n_in,
                              void* d_out, int out_size, void* d_ws, size_t ws_size,
                              hipStream_t stream) {
    (void)n_in; (void)d_ws; (void)ws_size; (void)out_size;

    const float* rgb    = (const float*)d_in[0];
    const float* sdf    = (const float*)d_in[1];
    const float* z      = (const float*)d_in[2];
    const int*   beta_p = (const int*)d_in[3];

    const int n_rays = in_sizes[1] / SDFR_NS;  // 65536

    // output layout (f32): depth[N] | rgb[N*3] | sdf[N*96] | z[N*96]
    float* out_depth = (float*)d_out;
    float* out_rgb   = out_depth + n_rays;
    float* out_sdf   = out_rgb   + (size_t)n_rays * 3;
    float* out_z     = out_sdf   + (size_t)n_rays * SDFR_NS;

    const int grid = (n_rays + SDFR_RPB - 1) / SDFR_RPB;  // 2048
    sdf_render_kernel<<<grid, 256, 0, stream>>>(
        rgb, sdf, z, beta_p, out_depth, out_rgb, out_sdf, out_z, n_rays);
}